// Round 6
// baseline (1832.018 us; speedup 1.0000x reference)
//
#include <hip/hip_runtime.h>

// RNNModule: LSTM-like scan with shared gate pre-activation.
// B=128, L=256, D=512, H=1024, O=2.
//
//  k0_prep : transpose+convert Wh/Wx to bf16 col-major, bxh=bx+bh,
//            poison-fill hs (0xAA sentinel for k2's dataflow).
//  k1_xproj: xp[l][b][n] = bf16( x[b,l,:]@Wx[:,n] + bx[n] + bh[n] )
//  k2_scan : 256 steps, pure dataflow (no inter-WG barrier). 8 groups
//            (16 batch rows) x 8 WGs. WG = 256 thr (4 waves = 1 wave/SIMD,
//            launch_bounds(256,1) -> 512-VGPR budget). Wave owns 32 cols as
//            TWO 16-col tiles sharing every LDS B-fragment (halves LDS reads
//            vs R5) with Wh frags register-resident (256 VGPRs -- R5's
//            (512,2) capped VGPRs at 128 and silently demoted them to
//            per-step L2 reloads, the measured bottleneck).
//            Exchange: producers st8 sc1 (coherence point); consumers stage
//            the group's 32 KB h-slice into LDS once per WG with sc0+sc1
//            loads polled against the poison sentinel.
//  k3_out  : out[b*L+l] = mask ? sigmoid(hs[l][b]@Wo + bo) : (0,1)

#define B_ 128
#define L_ 256
#define D_ 512
#define H_ 1024

#define POISON64 0xAAAAAAAAAAAAAAAAull

typedef __attribute__((ext_vector_type(8))) short short8;
typedef __attribute__((ext_vector_type(4))) float f32x4;
typedef __attribute__((ext_vector_type(2))) float f32x2;
typedef __attribute__((ext_vector_type(4))) unsigned short u16x4;
typedef __attribute__((ext_vector_type(4))) int i32x4;

__device__ __forceinline__ unsigned short f2bf(float f) {
    unsigned int u = __float_as_uint(f);
    return (unsigned short)((u + 0x8000u) >> 16);  // round-half-up to bf16
}
__device__ __forceinline__ float bf2f(unsigned short s) {
    return __uint_as_float(((unsigned int)s) << 16);
}

// agent-scope 8B atomic store: write-through to the coherence point (L3)
__device__ __forceinline__ void st8(unsigned short* p, unsigned long long v) {
    __hip_atomic_store((unsigned long long*)p, v,
                       __ATOMIC_RELAXED, __HIP_MEMORY_SCOPE_AGENT);
}

// 16B load bypassing BOTH L1 (sc0) and the non-coherent XCD L2 (sc1):
// reads the coherence point. 8B halves arrive untorn (producer stores are
// 8B atomics; each half is validated against the sentinel separately).
template<int OFF>
__device__ __forceinline__ i32x4 ld16cc(const unsigned short* p) {
    i32x4 r;
    asm volatile("global_load_dwordx4 %0, %1, off offset:%2 sc0 sc1"
                 : "=v"(r) : "v"(p), "i"(OFF) : "memory");
    return r;
}
// drain vmcnt and pin 4 tied values so no use is scheduled earlier
__device__ __forceinline__ void wait_vm0(i32x4& a, i32x4& b, i32x4& c, i32x4& d) {
    asm volatile("s_waitcnt vmcnt(0)" : "+v"(a), "+v"(b), "+v"(c), "+v"(d));
}
__device__ __forceinline__ bool pois(const i32x4 v) {
    bool h0 = (v.x == (int)0xAAAAAAAAu) && (v.y == (int)0xAAAAAAAAu);
    bool h1 = (v.z == (int)0xAAAAAAAAu) && (v.w == (int)0xAAAAAAAAu);
    return h0 | h1;
}

// ---------------------------------------------------------------- k0: prep
__global__ __launch_bounds__(256) void k0_prep(
    const float* __restrict__ Wh, const float* __restrict__ Wx,
    const float* __restrict__ bh, const float* __restrict__ bx,
    unsigned short* __restrict__ Whb_t, unsigned short* __restrict__ Wxb_t,
    float* __restrict__ bxh, unsigned short* __restrict__ hs)
{
    const int stride = gridDim.x * blockDim.x;
    const int t0 = blockIdx.x * blockDim.x + threadIdx.x;
    for (int i = t0; i < H_ * H_; i += stride) {
        int n = i >> 10, k = i & 1023;
        Whb_t[i] = f2bf(Wh[k * H_ + n]);
    }
    for (int i = t0; i < H_ * D_; i += stride) {
        int n = i >> 9, k = i & 511;
        Wxb_t[i] = f2bf(Wx[k * H_ + n]);
    }
    for (int i = t0; i < H_; i += stride) bxh[i] = bx[i] + bh[i];
    // poison-fill hs: k2's sentinel must not depend on harness pre-state
    unsigned long long* hp = (unsigned long long*)hs;
    const int nq = (L_ * B_ * H_) / 4;
    for (int i = t0; i < nq; i += stride) hp[i] = POISON64;
}

// ------------------------------------------------------------ k1: x @ Wx
// Operand-swapped MFMA (A=Wx^T frag, B=x frag): D[row=outcol][col=batch],
// so each lane's 4 results are 4 consecutive n -> 8B store into xp[l][b][n].
__global__ __launch_bounds__(256) void k1_xproj(
    const float* __restrict__ x, const unsigned short* __restrict__ Wxb_t,
    const float* __restrict__ bxh, unsigned short* __restrict__ xp)
{
    const int nt   = blockIdx.x & 3;
    const int mt   = blockIdx.x >> 2;
    const int w    = threadIdx.x >> 6;
    const int lane = threadIdx.x & 63;
    const int m    = lane & 15, q = lane >> 4;
    const int m0   = mt * 64;
    const int l    = m0 >> 7;
    const int brow = (m0 & 127) + w * 16;
    const int n0   = nt * 256;

    const float* ap = x + ((size_t)(brow + m) * L_ + l) * D_ + q * 8;

    f32x4 acc[16];
#pragma unroll
    for (int t = 0; t < 16; ++t) acc[t] = (f32x4){0.f, 0.f, 0.f, 0.f};

#pragma unroll 4
    for (int kk = 0; kk < 16; ++kk) {
        f32x4 av0 = *(const f32x4*)(ap + kk * 32);
        f32x4 av1 = *(const f32x4*)(ap + kk * 32 + 4);
        short8 a8;
        a8[0] = (short)f2bf(av0[0]); a8[1] = (short)f2bf(av0[1]);
        a8[2] = (short)f2bf(av0[2]); a8[3] = (short)f2bf(av0[3]);
        a8[4] = (short)f2bf(av1[0]); a8[5] = (short)f2bf(av1[1]);
        a8[6] = (short)f2bf(av1[2]); a8[7] = (short)f2bf(av1[3]);
#pragma unroll
        for (int t = 0; t < 16; ++t) {
            short8 b8 = *(const short8*)(Wxb_t +
                        (size_t)(n0 + t * 16 + m) * D_ + kk * 32 + q * 8);
            acc[t] = __builtin_amdgcn_mfma_f32_16x16x32_bf16(b8, a8, acc[t], 0, 0, 0);
        }
    }

#pragma unroll
    for (int t = 0; t < 16; ++t) {
        const int c0 = n0 + t * 16 + q * 4;       // 4 consecutive out-cols
        f32x4 bias = *(const f32x4*)(bxh + c0);
        u16x4 o;
#pragma unroll
        for (int r = 0; r < 4; ++r) o[r] = f2bf(acc[t][r] + bias[r]);
        *(u16x4*)(xp + ((size_t)l * B_ + brow + m) * H_ + c0) = o;
    }
}

// ------------------------------------------------------------- k2: scan
// Grid: 64 WGs x 256 thr (4 waves -> 1 wave/SIMD, 512-VGPR budget).
// group g=blk&7 (batch rows g*16..+15), wg=blk>>3 (cols wg*128..+127;
// wave w owns 32 cols = 2 tiles sharing each LDS B-fragment).
__global__ __launch_bounds__(256, 1) void k2_scan(
    const unsigned short* __restrict__ Whb_t,
    const unsigned short* __restrict__ xp,
    unsigned short* __restrict__ hs)
{
    // rows padded to 1032 shorts (2064 B): bank advance 4/row -> fragment
    // reads and staging writes land at free 2-way conflicts only.
    __shared__ unsigned short buf[2][16][1032];

    const int g    = blockIdx.x & 7;
    const int wg   = blockIdx.x >> 3;
    const int tid  = threadIdx.x;
    const int w    = tid >> 6;
    const int lane = tid & 63;
    const int mb   = lane & 15, q = lane >> 4;
    const int b0   = g * 16;
    const int colw = wg * 128 + w * 32;      // wave's 32 cols (2 tiles)

    // persistent A fragments: Wh^T[colw + t*16 + mb][k], k = kk*32 + q*8 + j
    // 64 x short8 = 256 VGPRs, resident for the whole scan.
    short8 afrag[64];
#pragma unroll
    for (int t = 0; t < 2; ++t) {
        const unsigned short* wp = Whb_t + (size_t)(colw + t * 16 + mb) * H_ + q * 8;
#pragma unroll
        for (int kk = 0; kk < 32; ++kk)
            afrag[t * 32 + kk] = *(const short8*)(wp + kk * 32);
    }

    // staging mapping: thread -> row srow (16 rows), 16B-chunks sci + 16i (i<8)
    const int srow = tid >> 4;   // 0..15
    const int sci  = tid & 15;   // 0..15

    float c[8] = {0.f,0.f,0.f,0.f, 0.f,0.f,0.f,0.f};   // cell state, 2 tiles x 4

    for (int l = 0; l < L_; ++l) {
        unsigned short* lbuf = &buf[l & 1][0][0];
        if (l > 0) {
            // ---- stage h[l-1] (16 x 1024, 32 KB) from L3 into LDS, once/WG
            const unsigned short* gp =
                hs + ((size_t)(l - 1) * B_ + b0 + srow) * H_ + sci * 8;
            i32x4 v0, v1, v2, v3, v4, v5, v6, v7;
            for (;;) {
                v0 = ld16cc<0>(gp);    v1 = ld16cc<256>(gp);
                v2 = ld16cc<512>(gp);  v3 = ld16cc<768>(gp);
                v4 = ld16cc<1024>(gp); v5 = ld16cc<1280>(gp);
                v6 = ld16cc<1536>(gp); v7 = ld16cc<1792>(gp);
                wait_vm0(v0, v1, v2, v3);
                wait_vm0(v4, v5, v6, v7);
                if (!(pois(v0) | pois(v1) | pois(v2) | pois(v3) |
                      pois(v4) | pois(v5) | pois(v6) | pois(v7))) break;
                __builtin_amdgcn_s_sleep(1);
            }
            unsigned short* lp = lbuf + srow * 1032 + sci * 8;
            *(i32x4*)(lp)        = v0;  *(i32x4*)(lp + 128)  = v1;
            *(i32x4*)(lp + 256)  = v2;  *(i32x4*)(lp + 384)  = v3;
            *(i32x4*)(lp + 512)  = v4;  *(i32x4*)(lp + 640)  = v5;
            *(i32x4*)(lp + 768)  = v6;  *(i32x4*)(lp + 896)  = v7;
        }
        __syncthreads();

        f32x4 acc[8];   // [tile][k-interleave 4]
#pragma unroll
        for (int i = 0; i < 8; ++i) acc[i] = (f32x4){0.f, 0.f, 0.f, 0.f};
        if (l > 0) {
            // B fragments from LDS: lane (mb,q) reads h[mb][kb*32+q*8 ..+7];
            // each fragment feeds BOTH col-tiles (2 MFMAs per ds_read_b128).
            const unsigned short* rp = lbuf + mb * 1032 + q * 8;
#pragma unroll
            for (int kb = 0; kb < 32; kb += 4) {
                short8 bb0 = *(const short8*)(rp + (kb + 0) * 32);
                short8 bb1 = *(const short8*)(rp + (kb + 1) * 32);
                short8 bb2 = *(const short8*)(rp + (kb + 2) * 32);
                short8 bb3 = *(const short8*)(rp + (kb + 3) * 32);
                acc[0] = __builtin_amdgcn_mfma_f32_16x16x32_bf16(afrag[kb + 0], bb0, acc[0], 0, 0, 0);
                acc[4] = __builtin_amdgcn_mfma_f32_16x16x32_bf16(afrag[32 + kb + 0], bb0, acc[4], 0, 0, 0);
                acc[1] = __builtin_amdgcn_mfma_f32_16x16x32_bf16(afrag[kb + 1], bb1, acc[1], 0, 0, 0);
                acc[5] = __builtin_amdgcn_mfma_f32_16x16x32_bf16(afrag[32 + kb + 1], bb1, acc[5], 0, 0, 0);
                acc[2] = __builtin_amdgcn_mfma_f32_16x16x32_bf16(afrag[kb + 2], bb2, acc[2], 0, 0, 0);
                acc[6] = __builtin_amdgcn_mfma_f32_16x16x32_bf16(afrag[32 + kb + 2], bb2, acc[6], 0, 0, 0);
                acc[3] = __builtin_amdgcn_mfma_f32_16x16x32_bf16(afrag[kb + 3], bb3, acc[3], 0, 0, 0);
                acc[7] = __builtin_amdgcn_mfma_f32_16x16x32_bf16(afrag[32 + kb + 3], bb3, acc[7], 0, 0, 0);
            }
        }
        // gate math per tile: lane (mb,q) -> batch b0+mb, cols colw+t*16+q*4+r
#pragma unroll
        for (int t = 0; t < 2; ++t) {
            u16x4 xv = *(const u16x4*)(xp + ((size_t)l * B_ + b0 + mb) * H_
                                          + colw + t * 16 + q * 4);
            u16x4 o;
#pragma unroll
            for (int r = 0; r < 4; ++r) {
                float z  = acc[4*t][r] + acc[4*t+1][r] + acc[4*t+2][r]
                         + acc[4*t+3][r] + bf2f(xv[r]);
                float e  = __expf(-z);
                float sg = 1.f / (1.f + e);           // sigmoid(z)
                float gg = 2.f / (1.f + e * e) - 1.f; // tanh(z) via same exp
                c[4*t+r] = sg * (c[4*t+r] + gg);
                float ec = __expf(-2.f * c[4*t+r]);
                float th = 2.f / (1.f + ec) - 1.f;    // tanh(c)
                o[r] = f2bf(sg * th);
            }
            union { u16x4 v; unsigned long long u; } hu;
            hu.v = o;
            if (hu.u == POISON64) hu.u ^= 1ull;       // never store the sentinel
            st8(hs + ((size_t)l * B_ + b0 + mb) * H_ + colw + t * 16 + q * 4, hu.u);
        }
    }
}

// ------------------------------------------------------------- k3: output
__global__ __launch_bounds__(256) void k3_out(
    const unsigned short* __restrict__ hs,
    const float* __restrict__ Wo, const float* __restrict__ bo,
    const int* __restrict__ slen, float* __restrict__ out)
{
    const int w    = threadIdx.x >> 6;
    const int lane = threadIdx.x & 63;
    const int r    = blockIdx.x * 4 + w;   // r = b*L + l
    const int b    = r >> 8;
    const int l    = r & 255;

    const unsigned short* hp = hs + ((size_t)l * B_ + b) * H_ + lane * 16;
    const float* wp = Wo + (size_t)lane * 32;
    float u0 = 0.f, u1 = 0.f;
#pragma unroll
    for (int j0 = 0; j0 < 16; j0 += 8) {
        short8 hv = *(const short8*)(hp + j0);
#pragma unroll
        for (int j = 0; j < 8; ++j) {
            float h = bf2f((unsigned short)hv[j]);
            f32x2 wv = *(const f32x2*)(wp + (j0 + j) * 2);
            u0 += h * wv[0];
            u1 += h * wv[1];
        }
    }
#pragma unroll
    for (int off = 32; off; off >>= 1) {
        u0 += __shfl_down(u0, off);
        u1 += __shfl_down(u1, off);
    }
    if (lane == 0) {
        float o0, o1;
        if (l <= slen[b]) {
            o0 = 1.f / (1.f + __expf(-(u0 + bo[0])));
            o1 = 1.f / (1.f + __expf(-(u1 + bo[1])));
        } else {
            o0 = 0.f; o1 = 1.f;
        }
        out[(size_t)r * 2]     = o0;
        out[(size_t)r * 2 + 1] = o1;
    }
}

// ----------------------------------------------------------------- launch
extern "C" void kernel_launch(void* const* d_in, const int* in_sizes, int n_in,
                              void* d_out, int out_size, void* d_ws, size_t ws_size,
                              hipStream_t stream)
{
    const float* x    = (const float*)d_in[0];
    const int*   slen = (const int*)d_in[1];
    const float* Wh   = (const float*)d_in[2];
    const float* bh   = (const float*)d_in[3];
    const float* Wx   = (const float*)d_in[4];
    const float* bx   = (const float*)d_in[5];
    const float* Wo   = (const float*)d_in[6];
    const float* bo   = (const float*)d_in[7];
    float* out = (float*)d_out;

    char* ws = (char*)d_ws;
    unsigned short* Whb_t = (unsigned short*)(ws);                     // 2 MiB
    unsigned short* Wxb_t = (unsigned short*)(ws + (2u << 20));        // 1 MiB
    float*          bxh   = (float*)(ws + (3u << 20));                 // 4 KiB
    unsigned short* xp    = (unsigned short*)(ws + (4u << 20));        // 64 MiB
    unsigned short* hs    = (unsigned short*)(ws + (68u << 20));       // 64 MiB

    k0_prep<<<512, 256, 0, stream>>>(Wh, Wx, bh, bx, Whb_t, Wxb_t, bxh, hs);
    k1_xproj<<<2048, 256, 0, stream>>>(x, Wxb_t, bxh, xp);
    k2_scan<<<64, 256, 0, stream>>>(Whb_t, xp, hs);
    k3_out<<<8192, 256, 0, stream>>>(hs, Wo, bo, slen, out);
}

// Round 7
// 1374.937 us; speedup vs baseline: 1.3324x; 1.3324x over previous
//
#include <hip/hip_runtime.h>

// RNNModule: LSTM-like scan with shared gate pre-activation.
// B=128, L=256, D=512, H=1024, O=2.
//
//  k0_prep : transpose+convert Wh/Wx to bf16 col-major, bxh=bx+bh, zero flags.
//  k1_xproj: xp[l][b][n] = bf16( x[b,l,:]@Wx[:,n] + bx[n] + bh[n] )
//  k2_scan : 256 steps, dataflow via per-wave RELEASE FLAGS (R7):
//            8 groups (16 batch rows) x 16 WGs (64 cols; wave owns 16 cols,
//            afrag = 128 VGPRs <= the 256 arch-VGPR ceiling that silently
//            demoted R5/R6's bigger tiles to per-step L2 reloads).
//            Producer wave: st8 h (sc1, coherence point) -> vmcnt(0) ->
//            flag=l+1 (sc1). Consumers poll 64 flags (4B/lane) then ONE
//            flag-gated 32 KB staging pass into dbuf LDS. No poison protocol.
//  k3_out  : out[b*L+l] = mask ? sigmoid(hs[l][b]@Wo + bo) : (0,1)

#define B_ 128
#define L_ 256
#define D_ 512
#define H_ 1024

typedef __attribute__((ext_vector_type(8))) short short8;
typedef __attribute__((ext_vector_type(4))) float f32x4;
typedef __attribute__((ext_vector_type(2))) float f32x2;
typedef __attribute__((ext_vector_type(4))) unsigned short u16x4;
typedef __attribute__((ext_vector_type(4))) int i32x4;

__device__ __forceinline__ unsigned short f2bf(float f) {
    unsigned int u = __float_as_uint(f);
    return (unsigned short)((u + 0x8000u) >> 16);  // round-half-up to bf16
}
__device__ __forceinline__ float bf2f(unsigned short s) {
    return __uint_as_float(((unsigned int)s) << 16);
}

// agent-scope 8B atomic store: write-through to the coherence point (L3)
__device__ __forceinline__ void st8(unsigned short* p, unsigned long long v) {
    __hip_atomic_store((unsigned long long*)p, v,
                       __ATOMIC_RELAXED, __HIP_MEMORY_SCOPE_AGENT);
}

// 16B load bypassing BOTH L1 (sc0) and the non-coherent XCD L2 (sc1):
// reads the coherence point (where producers' sc1 stores land).
template<int OFF>
__device__ __forceinline__ i32x4 ld16cc(const unsigned short* p) {
    i32x4 r;
    asm volatile("global_load_dwordx4 %0, %1, off offset:%2 sc0 sc1"
                 : "=v"(r) : "v"(p), "i"(OFF) : "memory");
    return r;
}
// drain vmcnt and pin 4 tied values so no use is scheduled earlier
__device__ __forceinline__ void wait_vm0(i32x4& a, i32x4& b, i32x4& c, i32x4& d) {
    asm volatile("s_waitcnt vmcnt(0)" : "+v"(a), "+v"(b), "+v"(c), "+v"(d) :: "memory");
}
// release-drain: own sc1 data stores ack'd at the coherence point
__device__ __forceinline__ void release_vm0() {
    asm volatile("s_waitcnt vmcnt(0)" ::: "memory");
}

// ---------------------------------------------------------------- k0: prep
__global__ __launch_bounds__(256) void k0_prep(
    const float* __restrict__ Wh, const float* __restrict__ Wx,
    const float* __restrict__ bh, const float* __restrict__ bx,
    unsigned short* __restrict__ Whb_t, unsigned short* __restrict__ Wxb_t,
    float* __restrict__ bxh, int* __restrict__ bar)
{
    const int stride = gridDim.x * blockDim.x;
    const int t0 = blockIdx.x * blockDim.x + threadIdx.x;
    for (int i = t0; i < H_ * H_; i += stride) {
        int n = i >> 10, k = i & 1023;
        Whb_t[i] = f2bf(Wh[k * H_ + n]);
    }
    for (int i = t0; i < H_ * D_; i += stride) {
        int n = i >> 9, k = i & 511;
        Wxb_t[i] = f2bf(Wx[k * H_ + n]);
    }
    for (int i = t0; i < H_; i += stride) bxh[i] = bx[i] + bh[i];
    // zero flags: 8 groups x 64 wave-flags x 16-int stride
    for (int i = t0; i < 8 * 1024; i += stride) bar[i] = 0;
}

// ------------------------------------------------------------ k1: x @ Wx
// Operand-swapped MFMA (A=Wx^T frag, B=x frag): D[row=outcol][col=batch],
// so each lane's 4 results are 4 consecutive n -> 8B store into xp[l][b][n].
__global__ __launch_bounds__(256) void k1_xproj(
    const float* __restrict__ x, const unsigned short* __restrict__ Wxb_t,
    const float* __restrict__ bxh, unsigned short* __restrict__ xp)
{
    const int nt   = blockIdx.x & 3;
    const int mt   = blockIdx.x >> 2;
    const int w    = threadIdx.x >> 6;
    const int lane = threadIdx.x & 63;
    const int m    = lane & 15, q = lane >> 4;
    const int m0   = mt * 64;
    const int l    = m0 >> 7;
    const int brow = (m0 & 127) + w * 16;
    const int n0   = nt * 256;

    const float* ap = x + ((size_t)(brow + m) * L_ + l) * D_ + q * 8;

    f32x4 acc[16];
#pragma unroll
    for (int t = 0; t < 16; ++t) acc[t] = (f32x4){0.f, 0.f, 0.f, 0.f};

#pragma unroll 4
    for (int kk = 0; kk < 16; ++kk) {
        f32x4 av0 = *(const f32x4*)(ap + kk * 32);
        f32x4 av1 = *(const f32x4*)(ap + kk * 32 + 4);
        short8 a8;
        a8[0] = (short)f2bf(av0[0]); a8[1] = (short)f2bf(av0[1]);
        a8[2] = (short)f2bf(av0[2]); a8[3] = (short)f2bf(av0[3]);
        a8[4] = (short)f2bf(av1[0]); a8[5] = (short)f2bf(av1[1]);
        a8[6] = (short)f2bf(av1[2]); a8[7] = (short)f2bf(av1[3]);
#pragma unroll
        for (int t = 0; t < 16; ++t) {
            short8 b8 = *(const short8*)(Wxb_t +
                        (size_t)(n0 + t * 16 + m) * D_ + kk * 32 + q * 8);
            acc[t] = __builtin_amdgcn_mfma_f32_16x16x32_bf16(b8, a8, acc[t], 0, 0, 0);
        }
    }

#pragma unroll
    for (int t = 0; t < 16; ++t) {
        const int c0 = n0 + t * 16 + q * 4;       // 4 consecutive out-cols
        f32x4 bias = *(const f32x4*)(bxh + c0);
        u16x4 o;
#pragma unroll
        for (int r = 0; r < 4; ++r) o[r] = f2bf(acc[t][r] + bias[r]);
        *(u16x4*)(xp + ((size_t)l * B_ + brow + m) * H_ + c0) = o;
    }
}

// ------------------------------------------------------------- k2: scan
// Grid: 128 WGs x 256 thr (4 waves, launch_bounds(256,1) -> 1 WG/CU, all
// co-resident). group g=blk&7 (batch rows g*16..+15; same-XCD under
// round-robin -- speed heuristic only), wg=blk>>3 in [0,16) (cols wg*64..+63;
// wave w owns 16). afrag 128 VGPRs, truly register-resident this time.
__global__ __launch_bounds__(256, 1) void k2_scan(
    const unsigned short* __restrict__ Whb_t,
    const unsigned short* __restrict__ xp,
    unsigned short* __restrict__ hs,
    int* __restrict__ bar)
{
    // rows padded to 1032 shorts: staging writes / fragment reads land on
    // mostly-free bank patterns (same scheme as R5/R6).
    __shared__ unsigned short buf[2][16][1032];

    const int g    = blockIdx.x & 7;
    const int wg   = blockIdx.x >> 3;        // 0..15
    const int tid  = threadIdx.x;
    const int w    = tid >> 6;               // 0..3
    const int lane = tid & 63;
    const int mb   = lane & 15, q = lane >> 4;
    const int b0   = g * 16;
    const int colw = wg * 64 + w * 16;       // wave's 16-col tile

    // persistent A fragments: Wh^T[colw+mb][k], k = kk*32 + q*8 + j
    // 32 x short8 = 128 VGPRs, resident for the whole scan (fits: ~210 < 256).
    short8 afrag[32];
    {
        const unsigned short* wp = Whb_t + (size_t)(colw + mb) * H_ + q * 8;
#pragma unroll
        for (int kk = 0; kk < 32; ++kk)
            afrag[kk] = *(const short8*)(wp + kk * 32);
    }

    int* flags  = bar + g * 1024;                   // 64 wave-flags, stride 16
    int* myflag = flags + (wg * 4 + w) * 16;

    // staging mapping: thread -> row srow, 16B-chunks sci + 16i (i<8)
    const int srow = tid >> 4;   // 0..15
    const int sci  = tid & 15;   // 0..15

    float c[4] = {0.f, 0.f, 0.f, 0.f};

    for (int l = 0; l < L_; ++l) {
        // xp addend (independent of recurrence): issue early
        u16x4 xv = *(const u16x4*)(xp + ((size_t)l * B_ + b0 + mb) * H_ + colw + q * 4);

        unsigned short* lbuf = &buf[l & 1][0][0];
        if (l > 0) {
            // wait: all 64 producer waves of this group published h(l-1).
            // lane i polls flag i -- one 4B sc1 load per lane per round.
            while (true) {
                int f = __hip_atomic_load(flags + lane * 16,
                         __ATOMIC_RELAXED, __HIP_MEMORY_SCOPE_AGENT);
                if (__all(f >= l)) break;
                __builtin_amdgcn_s_sleep(2);
            }
            // ONE flag-gated staging pass: h[l-1] slice (16x1024, 32 KB) -> LDS
            const unsigned short* gp =
                hs + ((size_t)(l - 1) * B_ + b0 + srow) * H_ + sci * 8;
            i32x4 v0, v1, v2, v3, v4, v5, v6, v7;
            v0 = ld16cc<0>(gp);    v1 = ld16cc<256>(gp);
            v2 = ld16cc<512>(gp);  v3 = ld16cc<768>(gp);
            v4 = ld16cc<1024>(gp); v5 = ld16cc<1280>(gp);
            v6 = ld16cc<1536>(gp); v7 = ld16cc<1792>(gp);
            wait_vm0(v0, v1, v2, v3);
            wait_vm0(v4, v5, v6, v7);
            unsigned short* lp = lbuf + srow * 1032 + sci * 8;
            *(i32x4*)(lp)        = v0;  *(i32x4*)(lp + 128)  = v1;
            *(i32x4*)(lp + 256)  = v2;  *(i32x4*)(lp + 384)  = v3;
            *(i32x4*)(lp + 512)  = v4;  *(i32x4*)(lp + 640)  = v5;
            *(i32x4*)(lp + 768)  = v6;  *(i32x4*)(lp + 896)  = v7;
        }
        __syncthreads();   // staging visible to all waves; dbuf protects l+1

        f32x4 acc0 = {0.f,0.f,0.f,0.f}, acc1 = {0.f,0.f,0.f,0.f};
        f32x4 acc2 = {0.f,0.f,0.f,0.f}, acc3 = {0.f,0.f,0.f,0.f};
        if (l > 0) {
            // B fragments from LDS: lane (mb,q) reads h[mb][kb*32+q*8 ..+7]
            const unsigned short* rp = lbuf + mb * 1032 + q * 8;
#pragma unroll
            for (int kb = 0; kb < 32; kb += 4) {
                short8 bb0 = *(const short8*)(rp + (kb + 0) * 32);
                short8 bb1 = *(const short8*)(rp + (kb + 1) * 32);
                short8 bb2 = *(const short8*)(rp + (kb + 2) * 32);
                short8 bb3 = *(const short8*)(rp + (kb + 3) * 32);
                acc0 = __builtin_amdgcn_mfma_f32_16x16x32_bf16(afrag[kb + 0], bb0, acc0, 0, 0, 0);
                acc1 = __builtin_amdgcn_mfma_f32_16x16x32_bf16(afrag[kb + 1], bb1, acc1, 0, 0, 0);
                acc2 = __builtin_amdgcn_mfma_f32_16x16x32_bf16(afrag[kb + 2], bb2, acc2, 0, 0, 0);
                acc3 = __builtin_amdgcn_mfma_f32_16x16x32_bf16(afrag[kb + 3], bb3, acc3, 0, 0, 0);
            }
        }
        // gate math: lane (mb,q) -> batch b0+mb, cols colw+q*4+r
        u16x4 o;
#pragma unroll
        for (int r = 0; r < 4; ++r) {
            float z  = acc0[r] + acc1[r] + acc2[r] + acc3[r] + bf2f(xv[r]);
            float e  = __expf(-z);
            float sg = 1.f / (1.f + e);           // sigmoid(z)
            float gg = 2.f / (1.f + e * e) - 1.f; // tanh(z) via same exp
            c[r] = sg * (c[r] + gg);
            float ec = __expf(-2.f * c[r]);
            float th = 2.f / (1.f + ec) - 1.f;    // tanh(c)
            o[r] = f2bf(sg * th);
        }
        union { u16x4 v; unsigned long long u; } hu;
        hu.v = o;
        st8(hs + ((size_t)l * B_ + b0 + mb) * H_ + colw + q * 4, hu.u);
        // per-wave release: own stores ack'd at coherence point, then flag
        release_vm0();
        if (lane == 0)
            __hip_atomic_store(myflag, l + 1,
                               __ATOMIC_RELAXED, __HIP_MEMORY_SCOPE_AGENT);
    }
}

// ------------------------------------------------------------- k3: output
// Safe to read hs with plain loads: kernel-dispatch boundaries perform the
// HSA acquire (L1/L2 invalidate), so no stale lines from k2/prior launches.
__global__ __launch_bounds__(256) void k3_out(
    const unsigned short* __restrict__ hs,
    const float* __restrict__ Wo, const float* __restrict__ bo,
    const int* __restrict__ slen, float* __restrict__ out)
{
    const int w    = threadIdx.x >> 6;
    const int lane = threadIdx.x & 63;
    const int r    = blockIdx.x * 4 + w;   // r = b*L + l
    const int b    = r >> 8;
    const int l    = r & 255;

    const unsigned short* hp = hs + ((size_t)l * B_ + b) * H_ + lane * 16;
    const float* wp = Wo + (size_t)lane * 32;
    float u0 = 0.f, u1 = 0.f;
#pragma unroll
    for (int j0 = 0; j0 < 16; j0 += 8) {
        short8 hv = *(const short8*)(hp + j0);
#pragma unroll
        for (int j = 0; j < 8; ++j) {
            float h = bf2f((unsigned short)hv[j]);
            f32x2 wv = *(const f32x2*)(wp + (j0 + j) * 2);
            u0 += h * wv[0];
            u1 += h * wv[1];
        }
    }
#pragma unroll
    for (int off = 32; off; off >>= 1) {
        u0 += __shfl_down(u0, off);
        u1 += __shfl_down(u1, off);
    }
    if (lane == 0) {
        float o0, o1;
        if (l <= slen[b]) {
            o0 = 1.f / (1.f + __expf(-(u0 + bo[0])));
            o1 = 1.f / (1.f + __expf(-(u1 + bo[1])));
        } else {
            o0 = 0.f; o1 = 1.f;
        }
        out[(size_t)r * 2]     = o0;
        out[(size_t)r * 2 + 1] = o1;
    }
}

// ----------------------------------------------------------------- launch
extern "C" void kernel_launch(void* const* d_in, const int* in_sizes, int n_in,
                              void* d_out, int out_size, void* d_ws, size_t ws_size,
                              hipStream_t stream)
{
    const float* x    = (const float*)d_in[0];
    const int*   slen = (const int*)d_in[1];
    const float* Wh   = (const float*)d_in[2];
    const float* bh   = (const float*)d_in[3];
    const float* Wx   = (const float*)d_in[4];
    const float* bx   = (const float*)d_in[5];
    const float* Wo   = (const float*)d_in[6];
    const float* bo   = (const float*)d_in[7];
    float* out = (float*)d_out;

    char* ws = (char*)d_ws;
    unsigned short* Whb_t = (unsigned short*)(ws);                     // 2 MiB
    unsigned short* Wxb_t = (unsigned short*)(ws + (2u << 20));        // 1 MiB
    float*          bxh   = (float*)(ws + (3u << 20));                 // 4 KiB
    int*            bar   = (int*)(ws + (3u << 20) + 65536);           // 32 KiB
    unsigned short* xp    = (unsigned short*)(ws + (4u << 20));        // 64 MiB
    unsigned short* hs    = (unsigned short*)(ws + (68u << 20));       // 64 MiB

    k0_prep<<<512, 256, 0, stream>>>(Wh, Wx, bh, bx, Whb_t, Wxb_t, bxh, bar);
    k1_xproj<<<2048, 256, 0, stream>>>(x, Wxb_t, bxh, xp);
    k2_scan<<<128, 256, 0, stream>>>(Whb_t, xp, hs, bar);
    k3_out<<<8192, 256, 0, stream>>>(hs, Wo, bo, slen, out);
}

// Round 8
// 1361.744 us; speedup vs baseline: 1.3453x; 1.0097x over previous
//
#include <hip/hip_runtime.h>

// RNNModule: LSTM-like scan with shared gate pre-activation.
// B=128, L=256, D=512, H=1024, O=2.
//
//  k0_prep : LDS-tiled transpose+convert Wh/Wx -> bf16 col-major (coalesced
//            both sides), bxh=bx+bh, zero flags.
//  k1_xproj: xp[l][b][n] = bf16( x[b,l,:]@Wx[:,n] + bx[n] + bh[n] )
//  k2_scan : 256 steps, dataflow via per-wave release flags. 8 groups
//            (16 batch rows) x 16 WGs (64 cols; wave owns 16 cols).
//            R8: afrag pinned in VGPRs via opaque inline-asm loads (LLVM
//            rematerialized plain loads back into the loop in R5-R7 ->
//            per-step L2 restream; VGPR_Count 104 proved it). Poll spins
//            without s_sleep; staging drain split vmcnt(4)/vmcnt(0).
//  k3_out  : out[b*L+l] = mask ? sigmoid(hs[l][b]@Wo + bo) : (0,1)

#define B_ 128
#define L_ 256
#define D_ 512
#define H_ 1024

typedef __attribute__((ext_vector_type(8))) short short8;
typedef __attribute__((ext_vector_type(4))) float f32x4;
typedef __attribute__((ext_vector_type(2))) float f32x2;
typedef __attribute__((ext_vector_type(4))) unsigned short u16x4;
typedef __attribute__((ext_vector_type(4))) int i32x4;

__device__ __forceinline__ unsigned short f2bf(float f) {
    unsigned int u = __float_as_uint(f);
    return (unsigned short)((u + 0x8000u) >> 16);  // round-half-up to bf16
}
__device__ __forceinline__ float bf2f(unsigned short s) {
    return __uint_as_float(((unsigned int)s) << 16);
}

// agent-scope 8B atomic store: write-through to the coherence point (L3)
__device__ __forceinline__ void st8(unsigned short* p, unsigned long long v) {
    __hip_atomic_store((unsigned long long*)p, v,
                       __ATOMIC_RELAXED, __HIP_MEMORY_SCOPE_AGENT);
}

// 16B load bypassing BOTH L1 (sc0) and the non-coherent XCD L2 (sc1):
// reads the coherence point (where producers' sc1 stores land).
template<int OFF>
__device__ __forceinline__ i32x4 ld16cc(const unsigned short* p) {
    i32x4 r;
    asm volatile("global_load_dwordx4 %0, %1, off offset:%2 sc0 sc1"
                 : "=v"(r) : "v"(p), "i"(OFF) : "memory");
    return r;
}
// staged drains: pin 4 tied values each so no use is scheduled earlier
__device__ __forceinline__ void wait_vm4(i32x4& a, i32x4& b, i32x4& c, i32x4& d) {
    asm volatile("s_waitcnt vmcnt(4)" : "+v"(a), "+v"(b), "+v"(c), "+v"(d) :: "memory");
}
__device__ __forceinline__ void wait_vm0(i32x4& a, i32x4& b, i32x4& c, i32x4& d) {
    asm volatile("s_waitcnt vmcnt(0)" : "+v"(a), "+v"(b), "+v"(c), "+v"(d) :: "memory");
}
// release-drain: own sc1 data stores ack'd at the coherence point
__device__ __forceinline__ void release_vm0() {
    asm volatile("s_waitcnt vmcnt(0)" ::: "memory");
}

// ---------------------------------------------------------------- k0: prep
// blk<256: Wh 64x64 tile transpose; blk<384: Wx tiles; blk 384: bxh+flags.
__global__ __launch_bounds__(256) void k0_prep(
    const float* __restrict__ Wh, const float* __restrict__ Wx,
    const float* __restrict__ bh, const float* __restrict__ bx,
    unsigned short* __restrict__ Whb_t, unsigned short* __restrict__ Wxb_t,
    float* __restrict__ bxh, int* __restrict__ bar)
{
    __shared__ float tile[64][65];
    const int blk = blockIdx.x;
    const int t   = threadIdx.x;
    const int c   = t & 63, r0 = t >> 6;

    if (blk < 256) {            // Wh (1024x1024) -> Whb_t[n][k]
        const int tk = (blk >> 4) * 64, tn = (blk & 15) * 64;
#pragma unroll
        for (int i = 0; i < 16; ++i) {
            int r = i * 4 + r0;
            tile[r][c] = Wh[(size_t)(tk + r) * H_ + tn + c];
        }
        __syncthreads();
#pragma unroll
        for (int i = 0; i < 16; ++i) {
            int r = i * 4 + r0;
            Whb_t[(size_t)(tn + r) * H_ + tk + c] = f2bf(tile[c][r]);
        }
    } else if (blk < 384) {     // Wx (512x1024) -> Wxb_t[n][k]
        const int bi = blk - 256;
        const int tk = (bi >> 4) * 64, tn = (bi & 15) * 64;
#pragma unroll
        for (int i = 0; i < 16; ++i) {
            int r = i * 4 + r0;
            tile[r][c] = Wx[(size_t)(tk + r) * H_ + tn + c];
        }
        __syncthreads();
#pragma unroll
        for (int i = 0; i < 16; ++i) {
            int r = i * 4 + r0;
            Wxb_t[(size_t)(tn + r) * D_ + tk + c] = f2bf(tile[c][r]);
        }
    } else {
        for (int i = t; i < H_; i += 256) bxh[i] = bx[i] + bh[i];
        for (int i = t; i < 8 * 1024; i += 256) bar[i] = 0;
    }
}

// ------------------------------------------------------------ k1: x @ Wx
// Operand-swapped MFMA (A=Wx^T frag, B=x frag): D[row=outcol][col=batch],
// so each lane's 4 results are 4 consecutive n -> 8B store into xp[l][b][n].
__global__ __launch_bounds__(256) void k1_xproj(
    const float* __restrict__ x, const unsigned short* __restrict__ Wxb_t,
    const float* __restrict__ bxh, unsigned short* __restrict__ xp)
{
    const int nt   = blockIdx.x & 3;
    const int mt   = blockIdx.x >> 2;
    const int w    = threadIdx.x >> 6;
    const int lane = threadIdx.x & 63;
    const int m    = lane & 15, q = lane >> 4;
    const int m0   = mt * 64;
    const int l    = m0 >> 7;
    const int brow = (m0 & 127) + w * 16;
    const int n0   = nt * 256;

    const float* ap = x + ((size_t)(brow + m) * L_ + l) * D_ + q * 8;

    f32x4 acc[16];
#pragma unroll
    for (int t = 0; t < 16; ++t) acc[t] = (f32x4){0.f, 0.f, 0.f, 0.f};

#pragma unroll 4
    for (int kk = 0; kk < 16; ++kk) {
        f32x4 av0 = *(const f32x4*)(ap + kk * 32);
        f32x4 av1 = *(const f32x4*)(ap + kk * 32 + 4);
        short8 a8;
        a8[0] = (short)f2bf(av0[0]); a8[1] = (short)f2bf(av0[1]);
        a8[2] = (short)f2bf(av0[2]); a8[3] = (short)f2bf(av0[3]);
        a8[4] = (short)f2bf(av1[0]); a8[5] = (short)f2bf(av1[1]);
        a8[6] = (short)f2bf(av1[2]); a8[7] = (short)f2bf(av1[3]);
#pragma unroll
        for (int t = 0; t < 16; ++t) {
            short8 b8 = *(const short8*)(Wxb_t +
                        (size_t)(n0 + t * 16 + m) * D_ + kk * 32 + q * 8);
            acc[t] = __builtin_amdgcn_mfma_f32_16x16x32_bf16(b8, a8, acc[t], 0, 0, 0);
        }
    }

#pragma unroll
    for (int t = 0; t < 16; ++t) {
        const int c0 = n0 + t * 16 + q * 4;       // 4 consecutive out-cols
        f32x4 bias = *(const f32x4*)(bxh + c0);
        u16x4 o;
#pragma unroll
        for (int r = 0; r < 4; ++r) o[r] = f2bf(acc[t][r] + bias[r]);
        *(u16x4*)(xp + ((size_t)l * B_ + brow + m) * H_ + c0) = o;
    }
}

// ------------------------------------------------------------- k2: scan
// Grid: 128 WGs x 256 thr (4 waves, launch_bounds(256,1)). group g=blk&7
// (batch rows g*16..+15), wg=blk>>3 in [0,16) (cols wg*64..+63; wave owns 16).
// afrag pinned via opaque asm loads -> truly register-resident.
__global__ __launch_bounds__(256, 1) void k2_scan(
    const unsigned short* __restrict__ Whb_t,
    const unsigned short* __restrict__ xp,
    unsigned short* __restrict__ hs,
    int* __restrict__ bar)
{
    __shared__ unsigned short buf[2][16][1032];

    const int g    = blockIdx.x & 7;
    const int wg   = blockIdx.x >> 3;        // 0..15
    const int tid  = threadIdx.x;
    const int w    = tid >> 6;               // 0..3
    const int lane = tid & 63;
    const int mb   = lane & 15, q = lane >> 4;
    const int b0   = g * 16;
    const int colw = wg * 64 + w * 16;       // wave's 16-col tile

    // persistent A fragments: Wh^T[colw+mb][k], k = kk*32 + q*8 + j.
    // Loaded via OPAQUE asm (cannot be rematerialized/sunk into the loop),
    // anchored after the drain -> 128 VGPRs live for the whole scan.
    short8 afrag[32];
    {
        const unsigned short* wp = Whb_t + (size_t)(colw + mb) * H_ + q * 8;
#pragma unroll
        for (int kk = 0; kk < 32; ++kk)
            asm volatile("global_load_dwordx4 %0, %1, off offset:%2"
                         : "=v"(afrag[kk]) : "v"(wp), "i"(kk * 64));
        asm volatile("s_waitcnt vmcnt(0)" ::: "memory");
#pragma unroll
        for (int kk = 0; kk < 32; ++kk)
            asm volatile("" : "+v"(afrag[kk]));
    }

    int* flags  = bar + g * 1024;                   // 64 wave-flags, stride 16
    int* myflag = flags + (wg * 4 + w) * 16;

    // staging mapping: thread -> row srow, 16B-chunks sci + 16i (i<8)
    const int srow = tid >> 4;   // 0..15
    const int sci  = tid & 15;   // 0..15

    float c[4] = {0.f, 0.f, 0.f, 0.f};

    for (int l = 0; l < L_; ++l) {
        // xp addend (independent of recurrence): issue early
        u16x4 xv = *(const u16x4*)(xp + ((size_t)l * B_ + b0 + mb) * H_ + colw + q * 4);

        unsigned short* lbuf = &buf[l & 1][0][0];
        if (l > 0) {
            // wait: all 64 producer waves of this group published h(l-1).
            // lane i polls flag i -- tight spin, no sleep (RT-bound anyway).
            while (true) {
                int f = __hip_atomic_load(flags + lane * 16,
                         __ATOMIC_RELAXED, __HIP_MEMORY_SCOPE_AGENT);
                if (__all(f >= l)) break;
            }
            // ONE staging pass: h[l-1] slice (16x1024, 32 KB) -> LDS.
            // Split drain: write first half while second half in flight.
            const unsigned short* gp =
                hs + ((size_t)(l - 1) * B_ + b0 + srow) * H_ + sci * 8;
            i32x4 v0, v1, v2, v3, v4, v5, v6, v7;
            v0 = ld16cc<0>(gp);    v1 = ld16cc<256>(gp);
            v2 = ld16cc<512>(gp);  v3 = ld16cc<768>(gp);
            v4 = ld16cc<1024>(gp); v5 = ld16cc<1280>(gp);
            v6 = ld16cc<1536>(gp); v7 = ld16cc<1792>(gp);
            unsigned short* lp = lbuf + srow * 1032 + sci * 8;
            wait_vm4(v0, v1, v2, v3);
            *(i32x4*)(lp)        = v0;  *(i32x4*)(lp + 128)  = v1;
            *(i32x4*)(lp + 256)  = v2;  *(i32x4*)(lp + 384)  = v3;
            wait_vm0(v4, v5, v6, v7);
            *(i32x4*)(lp + 512)  = v4;  *(i32x4*)(lp + 640)  = v5;
            *(i32x4*)(lp + 768)  = v6;  *(i32x4*)(lp + 896)  = v7;
        }
        __syncthreads();   // staging visible to all waves; dbuf protects l+1

        f32x4 acc0 = {0.f,0.f,0.f,0.f}, acc1 = {0.f,0.f,0.f,0.f};
        f32x4 acc2 = {0.f,0.f,0.f,0.f}, acc3 = {0.f,0.f,0.f,0.f};
        if (l > 0) {
            // B fragments from LDS: lane (mb,q) reads h[mb][kb*32+q*8 ..+7]
            const unsigned short* rp = lbuf + mb * 1032 + q * 8;
#pragma unroll
            for (int kb = 0; kb < 32; kb += 4) {
                short8 bb0 = *(const short8*)(rp + (kb + 0) * 32);
                short8 bb1 = *(const short8*)(rp + (kb + 1) * 32);
                short8 bb2 = *(const short8*)(rp + (kb + 2) * 32);
                short8 bb3 = *(const short8*)(rp + (kb + 3) * 32);
                acc0 = __builtin_amdgcn_mfma_f32_16x16x32_bf16(afrag[kb + 0], bb0, acc0, 0, 0, 0);
                acc1 = __builtin_amdgcn_mfma_f32_16x16x32_bf16(afrag[kb + 1], bb1, acc1, 0, 0, 0);
                acc2 = __builtin_amdgcn_mfma_f32_16x16x32_bf16(afrag[kb + 2], bb2, acc2, 0, 0, 0);
                acc3 = __builtin_amdgcn_mfma_f32_16x16x32_bf16(afrag[kb + 3], bb3, acc3, 0, 0, 0);
            }
        }
        // gate math: lane (mb,q) -> batch b0+mb, cols colw+q*4+r
        u16x4 o;
#pragma unroll
        for (int r = 0; r < 4; ++r) {
            float z  = acc0[r] + acc1[r] + acc2[r] + acc3[r] + bf2f(xv[r]);
            float e  = __expf(-z);
            float sg = 1.f / (1.f + e);           // sigmoid(z)
            float gg = 2.f / (1.f + e * e) - 1.f; // tanh(z) via same exp
            c[r] = sg * (c[r] + gg);
            float ec = __expf(-2.f * c[r]);
            float th = 2.f / (1.f + ec) - 1.f;    // tanh(c)
            o[r] = f2bf(sg * th);
        }
        union { u16x4 v; unsigned long long u; } hu;
        hu.v = o;
        st8(hs + ((size_t)l * B_ + b0 + mb) * H_ + colw + q * 4, hu.u);
        // per-wave release: own stores ack'd at coherence point, then flag
        release_vm0();
        if (lane == 0)
            __hip_atomic_store(myflag, l + 1,
                               __ATOMIC_RELAXED, __HIP_MEMORY_SCOPE_AGENT);
    }
}

// ------------------------------------------------------------- k3: output
// Kernel-dispatch boundaries perform the HSA acquire (cache invalidate), so
// plain loads of hs are safe here.
__global__ __launch_bounds__(256) void k3_out(
    const unsigned short* __restrict__ hs,
    const float* __restrict__ Wo, const float* __restrict__ bo,
    const int* __restrict__ slen, float* __restrict__ out)
{
    const int w    = threadIdx.x >> 6;
    const int lane = threadIdx.x & 63;
    const int r    = blockIdx.x * 4 + w;   // r = b*L + l
    const int b    = r >> 8;
    const int l    = r & 255;

    const unsigned short* hp = hs + ((size_t)l * B_ + b) * H_ + lane * 16;
    const float* wp = Wo + (size_t)lane * 32;
    float u0 = 0.f, u1 = 0.f;
#pragma unroll
    for (int j0 = 0; j0 < 16; j0 += 8) {
        short8 hv = *(const short8*)(hp + j0);
#pragma unroll
        for (int j = 0; j < 8; ++j) {
            float h = bf2f((unsigned short)hv[j]);
            f32x2 wv = *(const f32x2*)(wp + (j0 + j) * 2);
            u0 += h * wv[0];
            u1 += h * wv[1];
        }
    }
#pragma unroll
    for (int off = 32; off; off >>= 1) {
        u0 += __shfl_down(u0, off);
        u1 += __shfl_down(u1, off);
    }
    if (lane == 0) {
        float o0, o1;
        if (l <= slen[b]) {
            o0 = 1.f / (1.f + __expf(-(u0 + bo[0])));
            o1 = 1.f / (1.f + __expf(-(u1 + bo[1])));
        } else {
            o0 = 0.f; o1 = 1.f;
        }
        out[(size_t)r * 2]     = o0;
        out[(size_t)r * 2 + 1] = o1;
    }
}

// ----------------------------------------------------------------- launch
extern "C" void kernel_launch(void* const* d_in, const int* in_sizes, int n_in,
                              void* d_out, int out_size, void* d_ws, size_t ws_size,
                              hipStream_t stream)
{
    const float* x    = (const float*)d_in[0];
    const int*   slen = (const int*)d_in[1];
    const float* Wh   = (const float*)d_in[2];
    const float* bh   = (const float*)d_in[3];
    const float* Wx   = (const float*)d_in[4];
    const float* bx   = (const float*)d_in[5];
    const float* Wo   = (const float*)d_in[6];
    const float* bo   = (const float*)d_in[7];
    float* out = (float*)d_out;

    char* ws = (char*)d_ws;
    unsigned short* Whb_t = (unsigned short*)(ws);                     // 2 MiB
    unsigned short* Wxb_t = (unsigned short*)(ws + (2u << 20));        // 1 MiB
    float*          bxh   = (float*)(ws + (3u << 20));                 // 4 KiB
    int*            bar   = (int*)(ws + (3u << 20) + 65536);           // 32 KiB
    unsigned short* xp    = (unsigned short*)(ws + (4u << 20));        // 64 MiB
    unsigned short* hs    = (unsigned short*)(ws + (68u << 20));       // 64 MiB

    k0_prep<<<385, 256, 0, stream>>>(Wh, Wx, bh, bx, Whb_t, Wxb_t, bxh, bar);
    k1_xproj<<<2048, 256, 0, stream>>>(x, Wxb_t, bxh, xp);
    k2_scan<<<128, 256, 0, stream>>>(Whb_t, xp, hs, bar);
    k3_out<<<8192, 256, 0, stream>>>(hs, Wo, bo, slen, out);
}